// Round 7
// baseline (1484.006 us; speedup 1.0000x reference)
//
#include <hip/hip_runtime.h>
#include <math.h>

// ws layout (exactly 160 MiB):
//   Ph: _Float16 [9][64][1024][64]  (72 MiB)  "hi" fp16 split of proj
//   Pl: _Float16 [9][64][1024][64]  (72 MiB)  "lo" fp16 split of proj
//   attn: float [1024][4][1024]     (16 MiB)
// w order: 0=q,1=k,2=v,3=q_left,4=k_left,5=q_right,6=k_right,7=q_local,8=k_local
// layout per matrix: [bh][t][d]  EXCEPT w==2 (v) stored transposed [bh][d][t]

typedef _Float16 half8 __attribute__((ext_vector_type(8)));
typedef _Float16 half4v __attribute__((ext_vector_type(4)));
typedef float f32x4 __attribute__((ext_vector_type(4)));

#define MFMA16(A, B, C) __builtin_amdgcn_mfma_f32_16x16x32_f16(A, B, C, 0, 0, 0)

#define SMEM_ATTN ((16 * 1024 + 4 * 128) * 4)

// ---------------- split-fp16 MFMA GEMM: C = A * B^T + bias ----------------
template<int MODE>
__global__ __launch_bounds__(256, 2)
void gemm_mfma(const float* __restrict__ A, const float* __restrict__ B,
               const float* __restrict__ bias, float* __restrict__ C,
               _Float16* __restrict__ Ph, _Float16* __restrict__ Pl,
               int M, int N, int K) {
  __shared__ _Float16 Ah[128 * 64], Al[128 * 64], Bh[128 * 64], Bl[128 * 64];
  const int tid = threadIdx.x;
  const int m0 = blockIdx.x * 128, n0 = blockIdx.y * 128;
  const int wave = tid >> 6, lane = tid & 63;
  const int g2 = lane >> 4, c = lane & 15;
  const int wm = (wave >> 1) * 64, wn = (wave & 1) * 64;

  const int srow = tid >> 1;
  const int shalf = (tid & 1) * 32;
  const int swz = (srow & 7) << 3;
  const float* ap = A + (size_t)(m0 + srow) * K + shalf;
  const float* bp = B + (size_t)(n0 + srow) * K + shalf;

  f32x4 acc[4][4];
#pragma unroll
  for (int i = 0; i < 4; ++i)
#pragma unroll
    for (int j = 0; j < 4; ++j) acc[i][j] = (f32x4){0.f, 0.f, 0.f, 0.f};

  for (int k0 = 0; k0 < K; k0 += 64) {
    float4 av[8], bv[8];
#pragma unroll
    for (int u = 0; u < 8; ++u) {
      av[u] = *(const float4*)(ap + k0 + u * 4);
      bv[u] = *(const float4*)(bp + k0 + u * 4);
    }
    __syncthreads();
#pragma unroll
    for (int u = 0; u < 8; ++u) {
      const int cc = (shalf + u * 4) ^ swz;
      half4v h4a, l4a, h4b, l4b;
      const float* fa = (const float*)&av[u];
      const float* fb = (const float*)&bv[u];
#pragma unroll
      for (int e = 0; e < 4; ++e) {
        _Float16 ha = (_Float16)fa[e];
        h4a[e] = ha; l4a[e] = (_Float16)(fa[e] - (float)ha);
        _Float16 hb = (_Float16)fb[e];
        h4b[e] = hb; l4b[e] = (_Float16)(fb[e] - (float)hb);
      }
      *(half4v*)&Ah[srow * 64 + cc] = h4a;
      *(half4v*)&Al[srow * 64 + cc] = l4a;
      *(half4v*)&Bh[srow * 64 + cc] = h4b;
      *(half4v*)&Bl[srow * 64 + cc] = l4b;
    }
    __syncthreads();
#pragma unroll
    for (int ks = 0; ks < 2; ++ks) {
      const int kb = ks * 32 + 8 * g2;
      half8 a_h[4], a_l[4];
#pragma unroll
      for (int i = 0; i < 4; ++i) {
        const int row = wm + i * 16 + c;
        const int cc = kb ^ ((row & 7) << 3);
        a_h[i] = *(const half8*)&Ah[row * 64 + cc];
        a_l[i] = *(const half8*)&Al[row * 64 + cc];
      }
#pragma unroll
      for (int j = 0; j < 4; ++j) {
        const int rowb = wn + j * 16 + c;
        const int cc = kb ^ ((rowb & 7) << 3);
        const half8 b_h = *(const half8*)&Bh[rowb * 64 + cc];
        const half8 b_l = *(const half8*)&Bl[rowb * 64 + cc];
#pragma unroll
        for (int i = 0; i < 4; ++i) {
          acc[i][j] = MFMA16(a_h[i], b_h, acc[i][j]);
          acc[i][j] = MFMA16(a_h[i], b_l, acc[i][j]);
          acc[i][j] = MFMA16(a_l[i], b_h, acc[i][j]);
        }
      }
    }
  }

#pragma unroll
  for (int j = 0; j < 4; ++j) {
    const int nj = n0 + wn + j * 16 + c;
    const float bz = bias[nj];
    if (MODE == 0) {
#pragma unroll
      for (int i = 0; i < 4; ++i)
#pragma unroll
        for (int q = 0; q < 4; ++q) {
          const int mi = m0 + wm + i * 16 + 4 * g2 + q;
          C[(size_t)mi * N + nj] = acc[i][j][q] + bz;
        }
    } else {
      const int w = nj >> 10, hh = (nj >> 6) & 15, d = nj & 63;
      const float scale = (w == 0 || w == 7) ? 0.125f : 1.0f;
#pragma unroll
      for (int i = 0; i < 4; ++i)
#pragma unroll
        for (int q = 0; q < 4; ++q) {
          const int mi = m0 + wm + i * 16 + 4 * g2 + q;
          const int t = mi >> 2, b2 = mi & 3;
          const size_t bb = ((size_t)w * 64 + (b2 * 16 + hh)) * 65536;
          const size_t idx = (w == 2) ? bb + (size_t)d * 1024 + t
                                      : bb + (size_t)t * 64 + d;
          const float v = (acc[i][j][q] + bz) * scale;
          const _Float16 h16 = (_Float16)v;
          Ph[idx] = h16;
          Pl[idx] = (_Float16)(v - (float)h16);
        }
    }
  }
}

// ---------------- fused attention: tile-streamed, 4 barriers, low-VGPR ----------------
// grid 4096 (XCD-chunked), block 512 (8 waves), dynamic LDS 67584 B -> 2 WG/CU
__global__ __launch_bounds__(512, 4)
void attn_mfma(const _Float16* __restrict__ Ph, const _Float16* __restrict__ Pl,
               float* __restrict__ attnOut) {
  extern __shared__ float smem[];
  float* sP = smem;                  // [16][1024] fp32, XOR-swizzled
  float* sRed = smem + 16 * 1024;    // [4][16][8] wave-partial sums
  const int flat = blockIdx.x;
  const int nf = (flat & 7) * 512 + (flat >> 3);   // XCD-chunked
  const int bh = nf >> 6;
  const int t0 = (nf & 63) << 4;
  const int tid = threadIdx.x;
  const int wave = tid >> 6, lane = tid & 63;
  const int g2 = lane >> 4, c = lane & 15;
  const int sbase = wave << 7;

  auto pidx = [&](int row, int col) { return row * 1024 + (col ^ ((row & 7) << 2)); };
  auto mbase = [&](int w) { return ((size_t)w * 64 + bh) * 65536; };

  struct QF { half8 h0, h1, l0, l1; };
  auto loadQ = [&](int wq) {
    QF f;
    const _Float16* qh = Ph + mbase(wq) + (size_t)(t0 + c) * 64 + 8 * g2;
    const _Float16* ql = Pl + mbase(wq) + (size_t)(t0 + c) * 64 + 8 * g2;
    f.h0 = *(const half8*)qh; f.h1 = *(const half8*)(qh + 32);
    f.l0 = *(const half8*)ql; f.l1 = *(const half8*)(ql + 32);
    return f;
  };
  // one 16-col score tile: S[t0+4g2+q][sbase+16*tp+c] in reg q
  auto stile = [&](const QF& f, const _Float16* kbh, const _Float16* kbl, int tp) {
    const int s0 = sbase + tp * 16;
    const _Float16* kh = kbh + (size_t)(s0 + c) * 64 + 8 * g2;
    const _Float16* kl = kbl + (size_t)(s0 + c) * 64 + 8 * g2;
    const half8 bh0 = *(const half8*)kh, bh1 = *(const half8*)(kh + 32);
    const half8 bl0 = *(const half8*)kl, bl1 = *(const half8*)(kl + 32);
    f32x4 a = {0.f, 0.f, 0.f, 0.f};
    a = MFMA16(f.h0, bh0, a);
    a = MFMA16(f.h1, bh1, a);
    a = MFMA16(f.h0, bl0, a);
    a = MFMA16(f.h1, bl1, a);
    a = MFMA16(f.l0, bh0, a);
    a = MFMA16(f.l1, bh1, a);
    return a;
  };

  auto put = [&](int slot, f32x4 val) {
    if (c < 4) {
      const float x = (c == 0) ? val[0] : (c == 1) ? val[1] : (c == 2) ? val[2] : val[3];
      sRed[slot * 128 + (4 * g2 + c) * 8 + wave] = x;
    }
  };
  // total S over all waves; pref = sum over waves < this wave
  auto sum_pref = [&](int slot, f32x4& pref) {
    f32x4 S = {0.f, 0.f, 0.f, 0.f};
    pref = (f32x4){0.f, 0.f, 0.f, 0.f};
#pragma unroll
    for (int q = 0; q < 4; ++q) {
      const float* p = sRed + slot * 128 + (4 * g2 + q) * 8;
#pragma unroll
      for (int w = 0; w < 8; ++w) {
        const float t = p[w];
        S[q] += t;
        if (w < wave) pref[q] += t;
      }
    }
    return S;
  };
  auto scan16 = [&](f32x4& x) {
#pragma unroll
    for (int off = 1; off < 16; off <<= 1)
#pragma unroll
      for (int q = 0; q < 4; ++q) {
        const float u = __shfl_up(x[q], off, 64);
        if (c >= off) x[q] += u;
      }
  };
  auto sum16 = [&](f32x4& s) {
#pragma unroll
    for (int off = 1; off < 16; off <<= 1)
#pragma unroll
      for (int q = 0; q < 4; ++q) s[q] += __shfl_xor(s[q], off, 64);
  };
  const int tl = (lane & 48) | 15;   // last lane of this 16-lane group

  // ===== phase 1: LEFT -> unnormalized within-wave inclusive cumsum -> sP =====
  {
    const QF f = loadQ(3);
    const _Float16* kbh = Ph + mbase(4);
    const _Float16* kbl = Pl + mbase(4);
    f32x4 carry = {0.f, 0.f, 0.f, 0.f};
#pragma unroll
    for (int m = 0; m < 8; ++m) {
      f32x4 x = stile(f, kbh, kbl, m);
#pragma unroll
      for (int q = 0; q < 4; ++q) x[q] = __expf(x[q]);
      scan16(x);
      x += carry;
#pragma unroll
      for (int q = 0; q < 4; ++q) {
        carry[q] = __shfl(x[q], tl, 64);
        sP[pidx(4 * g2 + q, sbase + 16 * m + c)] = x[q];
      }
    }
    put(0, carry);
  }
  // ===== phase 2a: RIGHT wave totals =====
  {
    const QF f = loadQ(5);
    const _Float16* kbh = Ph + mbase(6);
    const _Float16* kbl = Pl + mbase(6);
    f32x4 s = {0.f, 0.f, 0.f, 0.f};
#pragma unroll
    for (int m = 0; m < 8; ++m) {
      f32x4 x = stile(f, kbh, kbl, m);
#pragma unroll
      for (int q = 0; q < 4; ++q) s[q] += __expf(x[q]);
    }
    sum16(s);
    put(1, s);
  }
  __syncthreads();                              // B1
  // ===== phase 2b: recompute RIGHT, scan, local_mask -> sP =====
  {
    f32x4 prefL, prefR;
    const f32x4 SL = sum_pref(0, prefL);
    const f32x4 SR = sum_pref(1, prefR);
    f32x4 invSL, invSR;
#pragma unroll
    for (int q = 0; q < 4; ++q) { invSL[q] = 1.f / SL[q]; invSR[q] = 1.f / SR[q]; }
    const QF f = loadQ(5);
    const _Float16* kbh = Ph + mbase(6);
    const _Float16* kbl = Pl + mbase(6);
    f32x4 carry = prefR;                        // unnormalized bf inclusive, pre-slice
    f32x4 aTail = prefL * invSL;                // af at col just before tile start
#pragma unroll
    for (int m = 0; m < 8; ++m) {
      f32x4 x = stile(f, kbh, kbl, m);
#pragma unroll
      for (int q = 0; q < 4; ++q) x[q] = __expf(x[q]);
      scan16(x);
      x += carry;                               // bfU inclusive (global)
      f32x4 bf, bfx, afi, afe, nc, nt;
#pragma unroll
      for (int q = 0; q < 4; ++q) {
        nc[q] = __shfl(x[q], tl, 64);
        const float u = __shfl_up(x[q], 1, 64);
        bfx[q] = ((c == 0) ? carry[q] : u) * invSR[q];
        bf[q] = x[q] * invSR[q];
        const int row = 4 * g2 + q, col = sbase + 16 * m + c;
        afi[q] = (sP[pidx(row, col)] + prefL[q]) * invSL[q];
        afe[q] = (c == 0) ? aTail[q] : (sP[pidx(row, col - 1)] + prefL[q]) * invSL[q];
        nt[q] = __shfl(afi[q], tl, 64);
      }
      const f32x4 mask = afi * (1.f - bfx) + (1.f - afe) * bf;
#pragma unroll
      for (int q = 0; q < 4; ++q)
        sP[pidx(4 * g2 + q, sbase + 16 * m + c)] = mask[q];
      carry = nc;
      aTail = nt;
    }
  }
  // ===== phase 3: LOCAL masked exp -> sP (unnormalized) =====
  {
    const QF f = loadQ(7);
    const _Float16* kbh = Ph + mbase(8);
    const _Float16* kbl = Pl + mbase(8);
    f32x4 s = {0.f, 0.f, 0.f, 0.f};
#pragma unroll
    for (int m = 0; m < 8; ++m) {
      f32x4 x = stile(f, kbh, kbl, m);
#pragma unroll
      for (int q = 0; q < 4; ++q) {
        const int ii = pidx(4 * g2 + q, sbase + 16 * m + c);
        const float e = __expf(x[q]) * sP[ii];
        sP[ii] = e;
        s[q] += e;
      }
    }
    sum16(s);
    put(2, s);
  }
  // ===== phase 4a: GLOBAL totals =====
  {
    const QF f = loadQ(0);
    const _Float16* kbh = Ph + mbase(1);
    const _Float16* kbl = Pl + mbase(1);
    f32x4 s = {0.f, 0.f, 0.f, 0.f};
#pragma unroll
    for (int m = 0; m < 8; ++m) {
      f32x4 x = stile(f, kbh, kbl, m);
#pragma unroll
      for (int q = 0; q < 4; ++q) s[q] += __expf(x[q]);
    }
    sum16(s);
    put(3, s);
  }
  __syncthreads();                              // B2
  // ===== phase 4b: recompute GLOBAL, final P = local*0.5/SO + expG*0.5/SG =====
  {
    f32x4 d0, d1;
    const f32x4 SO = sum_pref(2, d0);
    const f32x4 SG = sum_pref(3, d1);
    f32x4 scO, scG;
#pragma unroll
    for (int q = 0; q < 4; ++q) { scO[q] = 0.5f / SO[q]; scG[q] = 0.5f / SG[q]; }
    const QF f = loadQ(0);
    const _Float16* kbh = Ph + mbase(1);
    const _Float16* kbl = Pl + mbase(1);
#pragma unroll
    for (int m = 0; m < 8; ++m) {
      f32x4 x = stile(f, kbh, kbl, m);
#pragma unroll
      for (int q = 0; q < 4; ++q) {
        const int ii = pidx(4 * g2 + q, sbase + 16 * m + c);
        sP[ii] = sP[ii] * scO[q] + __expf(x[q]) * scG[q];
      }
    }
  }
  // no barrier: each wave's P slice is wave-private (in-order LDS pipe)

  // ===== PV via MFMA =====
  f32x4 cacc[4];
#pragma unroll
  for (int dt = 0; dt < 4; ++dt) cacc[dt] = (f32x4){0.f, 0.f, 0.f, 0.f};
  {
    const _Float16* vbh = Ph + mbase(2);
    const _Float16* vbl = Pl + mbase(2);
#pragma unroll
    for (int kk = 0; kk < 4; ++kk) {
      const int sk = sbase + kk * 32;
      float pv[8];
      *(float4*)&pv[0] = *(const float4*)&sP[pidx(c, sk + 8 * g2)];
      *(float4*)&pv[4] = *(const float4*)&sP[pidx(c, sk + 8 * g2 + 4)];
      half8 pah, pal;
#pragma unroll
      for (int j = 0; j < 8; ++j) {
        const _Float16 h16 = (_Float16)pv[j];
        pah[j] = h16;
        pal[j] = (_Float16)(pv[j] - (float)h16);
      }
#pragma unroll
      for (int dt = 0; dt < 4; ++dt) {
        const _Float16* vh = vbh + (size_t)(dt * 16 + c) * 1024 + sk + 8 * g2;
        const _Float16* vl = vbl + (size_t)(dt * 16 + c) * 1024 + sk + 8 * g2;
        const half8 bh8 = *(const half8*)vh;
        const half8 bl8 = *(const half8*)vl;
        cacc[dt] = MFMA16(pah, bh8, cacc[dt]);
        cacc[dt] = MFMA16(pah, bl8, cacc[dt]);
        cacc[dt] = MFMA16(pal, bh8, cacc[dt]);
      }
    }
  }
  __syncthreads();                  // B3: all PV reads done before sP reuse
#pragma unroll
  for (int dt = 0; dt < 4; ++dt)
#pragma unroll
    for (int q = 0; q < 4; ++q)
      sP[(wave * 16 + 4 * g2 + q) * 65 + dt * 16 + c] = cacc[dt][q];
  __syncthreads();                  // B4
  {
    const int b2 = bh >> 4, hh = bh & 15;
    for (int o = tid; o < 1024; o += 512) {
      const int r = o >> 6, d = o & 63;
      float a = 0.f;
#pragma unroll
      for (int w = 0; w < 8; ++w) a += sP[(w * 16 + r) * 65 + d];
      attnOut[((size_t)(t0 + r) * 4 + b2) * 1024 + hh * 64 + d] = a;
    }
  }
}

extern "C" void kernel_launch(void* const* d_in, const int* in_sizes, int n_in,
                              void* d_out, int out_size, void* d_ws, size_t ws_size,
                              hipStream_t stream) {
  const float* x     = (const float*)d_in[0];
  const float* w_in  = (const float*)d_in[1];
  const float* b_in  = (const float*)d_in[2];
  const float* w_out = (const float*)d_in[3];
  const float* b_out = (const float*)d_in[4];

  const size_t NP = (size_t)9 * 64 * 1024 * 64;
  _Float16* Ph = (_Float16*)d_ws;
  _Float16* Pl = Ph + NP;
  float* attn = (float*)(Pl + NP);

  (void)hipFuncSetAttribute((const void*)attn_mfma,
                            hipFuncAttributeMaxDynamicSharedMemorySize,
                            SMEM_ATTN);

  // proj = x @ w_in^T + b_in -> fp16 h/l split, head-major; v transposed
  gemm_mfma<1><<<dim3(32, 72), 256, 0, stream>>>(x, w_in, b_in, nullptr, Ph, Pl, 4096, 9216, 1024);
  // fused attention
  attn_mfma<<<4096, 512, SMEM_ATTN, stream>>>(Ph, Pl, attn);
  // out = attn @ w_out^T + b_out
  gemm_mfma<0><<<dim3(32, 8), 256, 0, stream>>>(attn, w_out, b_out, (float*)d_out, nullptr, nullptr, 4096, 1024, 1024);
}

// Round 8
// 1236.197 us; speedup vs baseline: 1.2005x; 1.2005x over previous
//
#include <hip/hip_runtime.h>
#include <math.h>

// ws layout (exactly 160 MiB):
//   Ph: _Float16 [9][64][1024][64]  (72 MiB)  "hi" fp16 split of proj
//   Pl: _Float16 [9][64][1024][64]  (72 MiB)  "lo" fp16 split of proj
//   attn: float [1024][4][1024]     (16 MiB)
// w order: 0=q,1=k,2=v,3=q_left,4=k_left,5=q_right,6=k_right,7=q_local,8=k_local
// layout per matrix: [bh][t][d]  EXCEPT w==2 (v) stored transposed [bh][d][t]

typedef _Float16 half8 __attribute__((ext_vector_type(8)));
typedef _Float16 half4v __attribute__((ext_vector_type(4)));
typedef float f32x4 __attribute__((ext_vector_type(4)));

#define MFMA16(A, B, C) __builtin_amdgcn_mfma_f32_16x16x32_f16(A, B, C, 0, 0, 0)

#define SMEM_ATTN ((16 * 1024 + 4 * 128) * 4)

// ---------------- split-fp16 MFMA GEMM: C = A * B^T + bias ----------------
template<int MODE>
__global__ __launch_bounds__(256, 2)
void gemm_mfma(const float* __restrict__ A, const float* __restrict__ B,
               const float* __restrict__ bias, float* __restrict__ C,
               _Float16* __restrict__ Ph, _Float16* __restrict__ Pl,
               int M, int N, int K) {
  __shared__ _Float16 Ah[128 * 64], Al[128 * 64], Bh[128 * 64], Bl[128 * 64];
  const int tid = threadIdx.x;
  const int m0 = blockIdx.x * 128, n0 = blockIdx.y * 128;
  const int wave = tid >> 6, lane = tid & 63;
  const int g2 = lane >> 4, c = lane & 15;
  const int wm = (wave >> 1) * 64, wn = (wave & 1) * 64;

  const int srow = tid >> 1;
  const int shalf = (tid & 1) * 32;
  const int swz = (srow & 7) << 3;
  const float* ap = A + (size_t)(m0 + srow) * K + shalf;
  const float* bp = B + (size_t)(n0 + srow) * K + shalf;

  f32x4 acc[4][4];
#pragma unroll
  for (int i = 0; i < 4; ++i)
#pragma unroll
    for (int j = 0; j < 4; ++j) acc[i][j] = (f32x4){0.f, 0.f, 0.f, 0.f};

  for (int k0 = 0; k0 < K; k0 += 64) {
    float4 av[8], bv[8];
#pragma unroll
    for (int u = 0; u < 8; ++u) {
      av[u] = *(const float4*)(ap + k0 + u * 4);
      bv[u] = *(const float4*)(bp + k0 + u * 4);
    }
    __syncthreads();
#pragma unroll
    for (int u = 0; u < 8; ++u) {
      const int cc = (shalf + u * 4) ^ swz;
      half4v h4a, l4a, h4b, l4b;
      const float* fa = (const float*)&av[u];
      const float* fb = (const float*)&bv[u];
#pragma unroll
      for (int e = 0; e < 4; ++e) {
        _Float16 ha = (_Float16)fa[e];
        h4a[e] = ha; l4a[e] = (_Float16)(fa[e] - (float)ha);
        _Float16 hb = (_Float16)fb[e];
        h4b[e] = hb; l4b[e] = (_Float16)(fb[e] - (float)hb);
      }
      *(half4v*)&Ah[srow * 64 + cc] = h4a;
      *(half4v*)&Al[srow * 64 + cc] = l4a;
      *(half4v*)&Bh[srow * 64 + cc] = h4b;
      *(half4v*)&Bl[srow * 64 + cc] = l4b;
    }
    __syncthreads();
#pragma unroll
    for (int ks = 0; ks < 2; ++ks) {
      const int kb = ks * 32 + 8 * g2;
      half8 a_h[4], a_l[4];
#pragma unroll
      for (int i = 0; i < 4; ++i) {
        const int row = wm + i * 16 + c;
        const int cc = kb ^ ((row & 7) << 3);
        a_h[i] = *(const half8*)&Ah[row * 64 + cc];
        a_l[i] = *(const half8*)&Al[row * 64 + cc];
      }
#pragma unroll
      for (int j = 0; j < 4; ++j) {
        const int rowb = wn + j * 16 + c;
        const int cc = kb ^ ((rowb & 7) << 3);
        const half8 b_h = *(const half8*)&Bh[rowb * 64 + cc];
        const half8 b_l = *(const half8*)&Bl[rowb * 64 + cc];
#pragma unroll
        for (int i = 0; i < 4; ++i) {
          acc[i][j] = MFMA16(a_h[i], b_h, acc[i][j]);
          acc[i][j] = MFMA16(a_h[i], b_l, acc[i][j]);
          acc[i][j] = MFMA16(a_l[i], b_h, acc[i][j]);
        }
      }
    }
  }

#pragma unroll
  for (int j = 0; j < 4; ++j) {
    const int nj = n0 + wn + j * 16 + c;
    const float bz = bias[nj];
    if (MODE == 0) {
#pragma unroll
      for (int i = 0; i < 4; ++i)
#pragma unroll
        for (int q = 0; q < 4; ++q) {
          const int mi = m0 + wm + i * 16 + 4 * g2 + q;
          C[(size_t)mi * N + nj] = acc[i][j][q] + bz;
        }
    } else {
      const int w = nj >> 10, hh = (nj >> 6) & 15, d = nj & 63;
      const float scale = (w == 0 || w == 7) ? 0.125f : 1.0f;
#pragma unroll
      for (int i = 0; i < 4; ++i)
#pragma unroll
        for (int q = 0; q < 4; ++q) {
          const int mi = m0 + wm + i * 16 + 4 * g2 + q;
          const int t = mi >> 2, b2 = mi & 3;
          const size_t bb = ((size_t)w * 64 + (b2 * 16 + hh)) * 65536;
          const size_t idx = (w == 2) ? bb + (size_t)d * 1024 + t
                                      : bb + (size_t)t * 64 + d;
          const float v = (acc[i][j][q] + bz) * scale;
          const _Float16 h16 = (_Float16)v;
          Ph[idx] = h16;
          Pl[idx] = (_Float16)(v - (float)h16);
        }
    }
  }
}

// -------- fused attention: all scores in regs, paired phases, 4 barriers --------
// grid 4096 (XCD-chunked), block 512 (8 waves), dynamic LDS 67584 B, 1 WG/CU
__global__ __launch_bounds__(512, 2)
void attn_mfma(const _Float16* __restrict__ Ph, const _Float16* __restrict__ Pl,
               float* __restrict__ attnOut) {
  extern __shared__ float smem[];
  float* sP = smem;                  // [16][1024] fp32, XOR-swizzled (final P)
  float* sRed = smem + 16 * 1024;    // [4][16][8] wave-partial sums
  const int flat = blockIdx.x;
  const int nf = (flat & 7) * 512 + (flat >> 3);   // XCD-chunked
  const int bh = nf >> 6;
  const int t0 = (nf & 63) << 4;
  const int tid = threadIdx.x;
  const int wave = tid >> 6, lane = tid & 63;
  const int g2 = lane >> 4, c = lane & 15;
  const int sbase = wave << 7;
  const int tl = (lane & 48) | 15;   // last lane of this 16-lane group

  auto pidx = [&](int row, int col) { return row * 1024 + (col ^ ((row & 7) << 2)); };
  auto mbase = [&](int w) { return ((size_t)w * 64 + bh) * 65536; };

  struct QF { half8 h0, h1, l0, l1; };
  auto loadQ = [&](int wq) {
    QF f;
    const _Float16* qh = Ph + mbase(wq) + (size_t)(t0 + c) * 64 + 8 * g2;
    const _Float16* ql = Pl + mbase(wq) + (size_t)(t0 + c) * 64 + 8 * g2;
    f.h0 = *(const half8*)qh; f.h1 = *(const half8*)(qh + 32);
    f.l0 = *(const half8*)ql; f.l1 = *(const half8*)(ql + 32);
    return f;
  };
  // one 16-col score tile: S[t0+4g2+q][sbase+16*tp+c] in acc reg q
  auto stile = [&](const QF& f, const _Float16* kbh, const _Float16* kbl, int tp) {
    const int s0 = sbase + tp * 16;
    const _Float16* kh = kbh + (size_t)(s0 + c) * 64 + 8 * g2;
    const _Float16* kl = kbl + (size_t)(s0 + c) * 64 + 8 * g2;
    const half8 bh0 = *(const half8*)kh, bh1 = *(const half8*)(kh + 32);
    const half8 bl0 = *(const half8*)kl, bl1 = *(const half8*)(kl + 32);
    f32x4 a = {0.f, 0.f, 0.f, 0.f};
    a = MFMA16(f.h0, bh0, a);
    a = MFMA16(f.h1, bh1, a);
    a = MFMA16(f.h0, bl0, a);
    a = MFMA16(f.h1, bl1, a);
    a = MFMA16(f.l0, bh0, a);
    a = MFMA16(f.l1, bh1, a);
    return a;
  };

  auto put = [&](int slot, f32x4 val) {
    if (c < 4) {
      const float x = (c == 0) ? val[0] : (c == 1) ? val[1] : (c == 2) ? val[2] : val[3];
      sRed[slot * 128 + (4 * g2 + c) * 8 + wave] = x;
    }
  };
  auto sum_pref = [&](int slot, f32x4& pref) {
    f32x4 S = {0.f, 0.f, 0.f, 0.f};
    pref = (f32x4){0.f, 0.f, 0.f, 0.f};
#pragma unroll
    for (int q = 0; q < 4; ++q) {
      const float* p = sRed + slot * 128 + (4 * g2 + q) * 8;
#pragma unroll
      for (int w = 0; w < 8; ++w) {
        const float t = p[w];
        S[q] += t;
        if (w < wave) pref[q] += t;
      }
    }
    return S;
  };
  auto scan16 = [&](f32x4& x) {
#pragma unroll
    for (int off = 1; off < 16; off <<= 1)
#pragma unroll
      for (int q = 0; q < 4; ++q) {
        const float u = __shfl_up(x[q], off, 64);
        if (c >= off) x[q] += u;
      }
  };
  auto sum16 = [&](f32x4& s) {
#pragma unroll
    for (int off = 1; off < 16; off <<= 1)
#pragma unroll
      for (int q = 0; q < 4; ++q) s[q] += __shfl_xor(s[q], off, 64);
  };

  f32x4 lv[8], rv[8], gv[8];

  // ===== phase LR: left+right scores, 16 independent load->MFMA chains =====
  {
    const QF fL = loadQ(3), fR = loadQ(5);
    const _Float16* k4h = Ph + mbase(4);
    const _Float16* k4l = Pl + mbase(4);
    const _Float16* k6h = Ph + mbase(6);
    const _Float16* k6l = Pl + mbase(6);
#pragma unroll
    for (int m = 0; m < 8; ++m) {
      lv[m] = stile(fL, k4h, k4l, m);
      rv[m] = stile(fR, k6h, k6l, m);
    }
  }
  // exp (independent), scan16 (independent), cheap carry accumulation
  {
#pragma unroll
    for (int m = 0; m < 8; ++m)
#pragma unroll
      for (int q = 0; q < 4; ++q) {
        lv[m][q] = __expf(lv[m][q]);
        rv[m][q] = __expf(rv[m][q]);
      }
#pragma unroll
    for (int m = 0; m < 8; ++m) { scan16(lv[m]); scan16(rv[m]); }
    f32x4 cl = {0.f, 0.f, 0.f, 0.f}, cr = {0.f, 0.f, 0.f, 0.f};
#pragma unroll
    for (int m = 0; m < 8; ++m) {
      f32x4 tL, tR;
#pragma unroll
      for (int q = 0; q < 4; ++q) {
        tL[q] = __shfl(lv[m][q], tl, 64);
        tR[q] = __shfl(rv[m][q], tl, 64);
      }
      lv[m] += cl;
      rv[m] += cr;
      cl += tL;
      cr += tR;
    }
    put(0, cl);
    put(1, cr);
  }
  __syncthreads();                              // B1
  // ===== mask (all regs): mask = af*(1-bfx) + (1-afx)*bf =====
  {
    f32x4 prefL, prefR;
    const f32x4 SL = sum_pref(0, prefL);
    const f32x4 SR = sum_pref(1, prefR);
    f32x4 invSL, invSR;
#pragma unroll
    for (int q = 0; q < 4; ++q) { invSL[q] = 1.f / SL[q]; invSR[q] = 1.f / SR[q]; }
#pragma unroll
    for (int m = 0; m < 8; ++m) {
      lv[m] = (lv[m] + prefL) * invSL;          // af inclusive, normalized
      rv[m] = (rv[m] + prefR) * invSR;          // bf inclusive, normalized
    }
    const f32x4 bL = prefL * invSL, bR = prefR * invSR;
#pragma unroll
    for (int m = 7; m >= 0; --m) {              // descending: lv[m-1] still af
      f32x4 afx, bfx;
#pragma unroll
      for (int q = 0; q < 4; ++q) {
        const float ua = __shfl_up(lv[m][q], 1, 64);
        const float ub = __shfl_up(rv[m][q], 1, 64);
        const float la = (m > 0) ? __shfl(lv[m - 1][q], tl, 64) : bL[q];
        const float lb = (m > 0) ? __shfl(rv[m - 1][q], tl, 64) : bR[q];
        afx[q] = (c == 0) ? la : ua;
        bfx[q] = (c == 0) ? lb : ub;
      }
      lv[m] = lv[m] * (1.f - bfx) + (1.f - afx) * rv[m];   // mask
    }
  }
  // ===== phase LG: local+global scores, interleaved =====
  {
    const QF fO = loadQ(7), fG = loadQ(0);
    const _Float16* k8h = Ph + mbase(8);
    const _Float16* k8l = Pl + mbase(8);
    const _Float16* k1h = Ph + mbase(1);
    const _Float16* k1l = Pl + mbase(1);
#pragma unroll
    for (int m = 0; m < 8; ++m) {
      rv[m] = stile(fO, k8h, k8l, m);           // local (reuse rv)
      gv[m] = stile(fG, k1h, k1l, m);           // global
    }
    f32x4 sO = {0.f, 0.f, 0.f, 0.f}, sG = {0.f, 0.f, 0.f, 0.f};
#pragma unroll
    for (int m = 0; m < 8; ++m)
#pragma unroll
      for (int q = 0; q < 4; ++q) {
        rv[m][q] = __expf(rv[m][q]) * lv[m][q];  // masked local exp
        gv[m][q] = __expf(gv[m][q]);
        sO[q] += rv[m][q];
        sG[q] += gv[m][q];
      }
    sum16(sO);
    sum16(sG);
    put(2, sO);
    put(3, sG);
  }
  __syncthreads();                              // B2
  // ===== final P = local*0.5/SO + global*0.5/SG -> sP =====
  {
    f32x4 d0, d1;
    const f32x4 SO = sum_pref(2, d0);
    const f32x4 SG = sum_pref(3, d1);
    f32x4 scO, scG;
#pragma unroll
    for (int q = 0; q < 4; ++q) { scO[q] = 0.5f / SO[q]; scG[q] = 0.5f / SG[q]; }
#pragma unroll
    for (int m = 0; m < 8; ++m)
#pragma unroll
      for (int q = 0; q < 4; ++q)
        sP[pidx(4 * g2 + q, sbase + 16 * m + c)] =
            rv[m][q] * scO[q] + gv[m][q] * scG[q];
  }
  // no barrier: each wave's P col-slice is wave-private (LDS pipe in-order)

  // ===== PV via MFMA =====
  f32x4 cacc[4];
#pragma unroll
  for (int dt = 0; dt < 4; ++dt) cacc[dt] = (f32x4){0.f, 0.f, 0.f, 0.f};
  {
    const _Float16* vbh = Ph + mbase(2);
    const _Float16* vbl = Pl + mbase(2);
#pragma unroll
    for (int kk = 0; kk < 4; ++kk) {
      const int sk = sbase + kk * 32;
      float pv[8];
      *(float4*)&pv[0] = *(const float4*)&sP[pidx(c, sk + 8 * g2)];
      *(float4*)&pv[4] = *(const float4*)&sP[pidx(c, sk + 8 * g2 + 4)];
      half8 pah, pal;
#pragma unroll
      for (int j = 0; j < 8; ++j) {
        const _Float16 h16 = (_Float16)pv[j];
        pah[j] = h16;
        pal[j] = (_Float16)(pv[j] - (float)h16);
      }
#pragma unroll
      for (int dt = 0; dt < 4; ++dt) {
        const _Float16* vh = vbh + (size_t)(dt * 16 + c) * 1024 + sk + 8 * g2;
        const _Float16* vl = vbl + (size_t)(dt * 16 + c) * 1024 + sk + 8 * g2;
        const half8 bh8 = *(const half8*)vh;
        const half8 bl8 = *(const half8*)vl;
        cacc[dt] = MFMA16(pah, bh8, cacc[dt]);
        cacc[dt] = MFMA16(pah, bl8, cacc[dt]);
        cacc[dt] = MFMA16(pal, bh8, cacc[dt]);
      }
    }
  }
  __syncthreads();                  // B3: all PV reads done before sP reuse
#pragma unroll
  for (int dt = 0; dt < 4; ++dt)
#pragma unroll
    for (int q = 0; q < 4; ++q)
      sP[(wave * 16 + 4 * g2 + q) * 65 + dt * 16 + c] = cacc[dt][q];
  __syncthreads();                  // B4
  {
    const int b2 = bh >> 4, hh = bh & 15;
    for (int o = tid; o < 1024; o += 512) {
      const int r = o >> 6, d = o & 63;
      float a = 0.f;
#pragma unroll
      for (int w = 0; w < 8; ++w) a += sP[(w * 16 + r) * 65 + d];
      attnOut[((size_t)(t0 + r) * 4 + b2) * 1024 + hh * 64 + d] = a;
    }
  }
}

extern "C" void kernel_launch(void* const* d_in, const int* in_sizes, int n_in,
                              void* d_out, int out_size, void* d_ws, size_t ws_size,
                              hipStream_t stream) {
  const float* x     = (const float*)d_in[0];
  const float* w_in  = (const float*)d_in[1];
  const float* b_in  = (const float*)d_in[2];
  const float* w_out = (const float*)d_in[3];
  const float* b_out = (const float*)d_in[4];

  const size_t NP = (size_t)9 * 64 * 1024 * 64;
  _Float16* Ph = (_Float16*)d_ws;
  _Float16* Pl = Ph + NP;
  float* attn = (float*)(Pl + NP);

  (void)hipFuncSetAttribute((const void*)attn_mfma,
                            hipFuncAttributeMaxDynamicSharedMemorySize,
                            SMEM_ATTN);

  // proj = x @ w_in^T + b_in -> fp16 h/l split, head-major; v transposed
  gemm_mfma<1><<<dim3(32, 72), 256, 0, stream>>>(x, w_in, b_in, nullptr, Ph, Pl, 4096, 9216, 1024);
  // fused attention
  attn_mfma<<<4096, 512, SMEM_ATTN, stream>>>(Ph, Pl, attn);
  // out = attn @ w_out^T + b_out
  gemm_mfma<0><<<dim3(32, 8), 256, 0, stream>>>(attn, w_out, b_out, (float*)d_out, nullptr, nullptr, 4096, 1024, 1024);
}

// Round 9
// 1131.856 us; speedup vs baseline: 1.3111x; 1.0922x over previous
//
#include <hip/hip_runtime.h>
#include <math.h>

// ws layout (exactly 160 MiB):
//   Ph: _Float16 [9][64][1024][64]  (72 MiB)  "hi" fp16 split of proj
//   Pl: _Float16 [9][64][1024][64]  (72 MiB)  "lo" fp16 split of proj
//   attn: float [1024][4][1024]     (16 MiB)
// w order: 0=q,1=k,2=v,3=q_left,4=k_left,5=q_right,6=k_right,7=q_local,8=k_local
// layout per matrix: [bh][t][d]  EXCEPT w==2 (v) stored transposed [bh][d][t]

typedef _Float16 half8 __attribute__((ext_vector_type(8)));
typedef _Float16 half4v __attribute__((ext_vector_type(4)));
typedef float f32x4 __attribute__((ext_vector_type(4)));

#define MFMA16(A, B, C) __builtin_amdgcn_mfma_f32_16x16x32_f16(A, B, C, 0, 0, 0)

#define SMEM_ATTN ((16 * 1024 + 4 * 128) * 4)

// ---------------- split-fp16 MFMA GEMM: C = A * B^T + bias ----------------
template<int MODE>
__global__ __launch_bounds__(256, 2)
void gemm_mfma(const float* __restrict__ A, const float* __restrict__ B,
               const float* __restrict__ bias, float* __restrict__ C,
               _Float16* __restrict__ Ph, _Float16* __restrict__ Pl,
               int M, int N, int K) {
  __shared__ _Float16 Ah[128 * 64], Al[128 * 64], Bh[128 * 64], Bl[128 * 64];
  const int tid = threadIdx.x;
  const int m0 = blockIdx.x * 128, n0 = blockIdx.y * 128;
  const int wave = tid >> 6, lane = tid & 63;
  const int g2 = lane >> 4, c = lane & 15;
  const int wm = (wave >> 1) * 64, wn = (wave & 1) * 64;

  const int srow = tid >> 1;
  const int shalf = (tid & 1) * 32;
  const int swz = (srow & 7) << 3;
  const float* ap = A + (size_t)(m0 + srow) * K + shalf;
  const float* bp = B + (size_t)(n0 + srow) * K + shalf;

  f32x4 acc[4][4];
#pragma unroll
  for (int i = 0; i < 4; ++i)
#pragma unroll
    for (int j = 0; j < 4; ++j) acc[i][j] = (f32x4){0.f, 0.f, 0.f, 0.f};

  for (int k0 = 0; k0 < K; k0 += 64) {
    float4 av[8], bv[8];
#pragma unroll
    for (int u = 0; u < 8; ++u) {
      av[u] = *(const float4*)(ap + k0 + u * 4);
      bv[u] = *(const float4*)(bp + k0 + u * 4);
    }
    __syncthreads();
#pragma unroll
    for (int u = 0; u < 8; ++u) {
      const int cc = (shalf + u * 4) ^ swz;
      half4v h4a, l4a, h4b, l4b;
      const float* fa = (const float*)&av[u];
      const float* fb = (const float*)&bv[u];
#pragma unroll
      for (int e = 0; e < 4; ++e) {
        _Float16 ha = (_Float16)fa[e];
        h4a[e] = ha; l4a[e] = (_Float16)(fa[e] - (float)ha);
        _Float16 hb = (_Float16)fb[e];
        h4b[e] = hb; l4b[e] = (_Float16)(fb[e] - (float)hb);
      }
      *(half4v*)&Ah[srow * 64 + cc] = h4a;
      *(half4v*)&Al[srow * 64 + cc] = l4a;
      *(half4v*)&Bh[srow * 64 + cc] = h4b;
      *(half4v*)&Bl[srow * 64 + cc] = l4b;
    }
    __syncthreads();
#pragma unroll
    for (int ks = 0; ks < 2; ++ks) {
      const int kb = ks * 32 + 8 * g2;
      half8 a_h[4], a_l[4];
#pragma unroll
      for (int i = 0; i < 4; ++i) {
        const int row = wm + i * 16 + c;
        const int cc = kb ^ ((row & 7) << 3);
        a_h[i] = *(const half8*)&Ah[row * 64 + cc];
        a_l[i] = *(const half8*)&Al[row * 64 + cc];
      }
#pragma unroll
      for (int j = 0; j < 4; ++j) {
        const int rowb = wn + j * 16 + c;
        const int cc = kb ^ ((rowb & 7) << 3);
        const half8 b_h = *(const half8*)&Bh[rowb * 64 + cc];
        const half8 b_l = *(const half8*)&Bl[rowb * 64 + cc];
#pragma unroll
        for (int i = 0; i < 4; ++i) {
          acc[i][j] = MFMA16(a_h[i], b_h, acc[i][j]);
          acc[i][j] = MFMA16(a_h[i], b_l, acc[i][j]);
          acc[i][j] = MFMA16(a_l[i], b_h, acc[i][j]);
        }
      }
    }
  }

#pragma unroll
  for (int j = 0; j < 4; ++j) {
    const int nj = n0 + wn + j * 16 + c;
    const float bz = bias[nj];
    if (MODE == 0) {
#pragma unroll
      for (int i = 0; i < 4; ++i)
#pragma unroll
        for (int q = 0; q < 4; ++q) {
          const int mi = m0 + wm + i * 16 + 4 * g2 + q;
          C[(size_t)mi * N + nj] = acc[i][j][q] + bz;
        }
    } else {
      const int w = nj >> 10, hh = (nj >> 6) & 15, d = nj & 63;
      const float scale = (w == 0 || w == 7) ? 0.125f : 1.0f;
#pragma unroll
      for (int i = 0; i < 4; ++i)
#pragma unroll
        for (int q = 0; q < 4; ++q) {
          const int mi = m0 + wm + i * 16 + 4 * g2 + q;
          const int t = mi >> 2, b2 = mi & 3;
          const size_t bb = ((size_t)w * 64 + (b2 * 16 + hh)) * 65536;
          const size_t idx = (w == 2) ? bb + (size_t)d * 1024 + t
                                      : bb + (size_t)t * 64 + d;
          const float v = (acc[i][j][q] + bz) * scale;
          const _Float16 h16 = (_Float16)v;
          Ph[idx] = h16;
          Pl[idx] = (_Float16)(v - (float)h16);
        }
    }
  }
}

// -------- fused attention: S^T orientation (s in registers), 4 barriers --------
// grid 4096 (XCD-chunked), block 512 (8 waves), dynamic LDS 67584 B, 1 WG/CU
// Per wave: lane c = t-row (t0+c); s = sbase + 16*m + 4*g2 + q  (m=tile, q=reg)
__global__ __launch_bounds__(512, 2)
void attn_mfma(const _Float16* __restrict__ Ph, const _Float16* __restrict__ Pl,
               float* __restrict__ attnOut) {
  extern __shared__ float smem[];
  float* sP = smem;                  // [16][1024] fp32, XOR-swizzled (final P)
  float* sRed = smem + 16 * 1024;    // [4][16][8] wave-partial sums
  const int flat = blockIdx.x;
  const int nf = (flat & 7) * 512 + (flat >> 3);   // XCD-chunked
  const int bh = nf >> 6;
  const int t0 = (nf & 63) << 4;
  const int tid = threadIdx.x;
  const int wave = tid >> 6, lane = tid & 63;
  const int g2 = lane >> 4, c = lane & 15;
  const int sbase = wave << 7;

  auto pidx = [&](int row, int col) { return row * 1024 + (col ^ ((row & 7) << 2)); };
  auto mbase = [&](int w) { return ((size_t)w * 64 + bh) * 65536; };

  struct QF { half8 h0, h1, l0, l1; };
  auto loadQ = [&](int wq) {
    QF f;
    const _Float16* qh = Ph + mbase(wq) + (size_t)(t0 + c) * 64 + 8 * g2;
    const _Float16* ql = Pl + mbase(wq) + (size_t)(t0 + c) * 64 + 8 * g2;
    f.h0 = *(const half8*)qh; f.h1 = *(const half8*)(qh + 32);
    f.l0 = *(const half8*)ql; f.l1 = *(const half8*)(ql + 32);
    return f;
  };
  // transposed score tile: C[s=16*tp+4g2+q][t=c] = K[s]·Q[t] (A=K, B=Q)
  auto stileT = [&](const QF& f, const _Float16* kbh, const _Float16* kbl, int tp) {
    const int s0 = sbase + tp * 16;
    const _Float16* kh = kbh + (size_t)(s0 + c) * 64 + 8 * g2;
    const _Float16* kl = kbl + (size_t)(s0 + c) * 64 + 8 * g2;
    const half8 ah0 = *(const half8*)kh, ah1 = *(const half8*)(kh + 32);
    const half8 al0 = *(const half8*)kl, al1 = *(const half8*)(kl + 32);
    f32x4 a = {0.f, 0.f, 0.f, 0.f};
    a = MFMA16(ah0, f.h0, a);
    a = MFMA16(ah1, f.h1, a);
    a = MFMA16(ah0, f.l0, a);
    a = MFMA16(ah1, f.l1, a);
    a = MFMA16(al0, f.h0, a);
    a = MFMA16(al1, f.h1, a);
    return a;
  };

  auto put = [&](int slot, float val) {
    if (lane < 16) sRed[slot * 128 + c * 8 + wave] = val;
  };
  auto sum_pref = [&](int slot, float& pref) {
    float S = 0.f;
    pref = 0.f;
    const float* p = sRed + slot * 128 + c * 8;
#pragma unroll
    for (int w = 0; w < 8; ++w) {
      const float t = p[w];
      S += t;
      if (w < wave) pref += t;
    }
    return S;
  };
  auto sum_only = [&](int slot) {
    float S = 0.f;
    const float* p = sRed + slot * 128 + c * 8;
#pragma unroll
    for (int w = 0; w < 8; ++w) S += p[w];
    return S;
  };
  // inclusive cumsum along s (regs): q-prefix, g2-scan, tile carry. returns wave total
  auto scan_s = [&](f32x4* v) {
    float carry = 0.f;
#pragma unroll
    for (int m = 0; m < 8; ++m) {
      v[m][1] += v[m][0];
      v[m][2] += v[m][1];
      v[m][3] += v[m][2];
      const float B = v[m][3];
      float sc = B;
      const float u1 = __shfl_up(sc, 16, 64);
      if (g2 >= 1) sc += u1;
      const float u2 = __shfl_up(sc, 32, 64);
      if (g2 >= 2) sc += u2;
      const float e = sc - B + carry;      // exclusive-of-g2 + prev tiles
      v[m][0] += e; v[m][1] += e; v[m][2] += e; v[m][3] += e;
      carry += __shfl(sc, 48 + c, 64);     // tile total from g2==3 lane
    }
    return carry;
  };
  auto rowsum = [&](const f32x4* v) {      // sum over this wave's 128 s, per t=c
    float s = 0.f;
#pragma unroll
    for (int m = 0; m < 8; ++m) s += (v[m][0] + v[m][1]) + (v[m][2] + v[m][3]);
    s += __shfl_xor(s, 16, 64);
    s += __shfl_xor(s, 32, 64);
    return s;
  };

  f32x4 lv[8], rv[8], gv[8];

  // ===== phase LR: left+right transposed scores, exp, cumsum =====
  {
    const QF fL = loadQ(3), fR = loadQ(5);
    const _Float16* k4h = Ph + mbase(4);
    const _Float16* k4l = Pl + mbase(4);
    const _Float16* k6h = Ph + mbase(6);
    const _Float16* k6l = Pl + mbase(6);
#pragma unroll
    for (int m = 0; m < 8; ++m) {
      lv[m] = stileT(fL, k4h, k4l, m);
      rv[m] = stileT(fR, k6h, k6l, m);
    }
#pragma unroll
    for (int m = 0; m < 8; ++m)
#pragma unroll
      for (int q = 0; q < 4; ++q) {
        lv[m][q] = __expf(lv[m][q]);
        rv[m][q] = __expf(rv[m][q]);
      }
    put(0, scan_s(lv));
    put(1, scan_s(rv));
  }
  __syncthreads();                              // B1
  // ===== mask: afx/bfx are lane-local (q-1) except q==0 boundaries =====
  {
    float prefL, prefR;
    const float SL = sum_pref(0, prefL);
    const float SR = sum_pref(1, prefR);
    const float invSL = 1.f / SL, invSR = 1.f / SR;
#pragma unroll
    for (int m = 0; m < 8; ++m)
#pragma unroll
      for (int q = 0; q < 4; ++q) {
        lv[m][q] = (lv[m][q] + prefL) * invSL;  // af inclusive, normalized
        rv[m][q] = (rv[m][q] + prefR) * invSR;  // bf inclusive, normalized
      }
    const float bL = prefL * invSL, bR = prefR * invSR;
#pragma unroll
    for (int m = 7; m >= 0; --m) {              // descending: lv[m-1] still af
      const float aU = __shfl_up(lv[m][3], 16, 64);
      const float bU = __shfl_up(rv[m][3], 16, 64);
      const float aM = (m > 0) ? __shfl(lv[m - 1][3], 48 + c, 64) : bL;
      const float bM = (m > 0) ? __shfl(rv[m - 1][3], 48 + c, 64) : bR;
      const float a0 = (g2 == 0) ? aM : aU;     // afx for q=0
      const float b0 = (g2 == 0) ? bM : bU;     // bfx for q=0
      f32x4 nm;
      nm[0] = lv[m][0] * (1.f - b0)        + (1.f - a0)        * rv[m][0];
      nm[1] = lv[m][1] * (1.f - rv[m][0])  + (1.f - lv[m][0])  * rv[m][1];
      nm[2] = lv[m][2] * (1.f - rv[m][1])  + (1.f - lv[m][1])  * rv[m][2];
      nm[3] = lv[m][3] * (1.f - rv[m][2])  + (1.f - lv[m][2])  * rv[m][3];
      lv[m] = nm;                               // local_mask
    }
  }
  // ===== phase LG: local+global transposed scores =====
  {
    const QF fO = loadQ(7), fG = loadQ(0);
    const _Float16* k8h = Ph + mbase(8);
    const _Float16* k8l = Pl + mbase(8);
    const _Float16* k1h = Ph + mbase(1);
    const _Float16* k1l = Pl + mbase(1);
#pragma unroll
    for (int m = 0; m < 8; ++m) {
      rv[m] = stileT(fO, k8h, k8l, m);          // local (reuse rv)
      gv[m] = stileT(fG, k1h, k1l, m);          // global
    }
#pragma unroll
    for (int m = 0; m < 8; ++m)
#pragma unroll
      for (int q = 0; q < 4; ++q) {
        rv[m][q] = __expf(rv[m][q]) * lv[m][q]; // masked local exp
        gv[m][q] = __expf(gv[m][q]);
      }
    put(2, rowsum(rv));
    put(3, rowsum(gv));
  }
  __syncthreads();                              // B2
  // ===== final P = local*0.5/SO + global*0.5/SG -> sP (float4 stores) =====
  {
    const float scO = 0.5f / sum_only(2);
    const float scG = 0.5f / sum_only(3);
#pragma unroll
    for (int m = 0; m < 8; ++m) {
      f32x4 pv4;
#pragma unroll
      for (int q = 0; q < 4; ++q) pv4[q] = rv[m][q] * scO + gv[m][q] * scG;
      *(f32x4*)&sP[pidx(c, sbase + 16 * m + 4 * g2)] = pv4;
    }
  }
  // no barrier: each wave's P col-slice is wave-private (LDS pipe in-order)

  // ===== PV via MFMA =====
  f32x4 cacc[4];
#pragma unroll
  for (int dt = 0; dt < 4; ++dt) cacc[dt] = (f32x4){0.f, 0.f, 0.f, 0.f};
  {
    const _Float16* vbh = Ph + mbase(2);
    const _Float16* vbl = Pl + mbase(2);
#pragma unroll
    for (int kk = 0; kk < 4; ++kk) {
      const int sk = sbase + kk * 32;
      float pv[8];
      *(float4*)&pv[0] = *(const float4*)&sP[pidx(c, sk + 8 * g2)];
      *(float4*)&pv[4] = *(const float4*)&sP[pidx(c, sk + 8 * g2 + 4)];
      half8 pah, pal;
#pragma unroll
      for (int j = 0; j < 8; ++j) {
        const _Float16 h16 = (_Float16)pv[j];
        pah[j] = h16;
        pal[j] = (_Float16)(pv[j] - (float)h16);
      }
#pragma unroll
      for (int dt = 0; dt < 4; ++dt) {
        const _Float16* vh = vbh + (size_t)(dt * 16 + c) * 1024 + sk + 8 * g2;
        const _Float16* vl = vbl + (size_t)(dt * 16 + c) * 1024 + sk + 8 * g2;
        const half8 bh8 = *(const half8*)vh;
        const half8 bl8 = *(const half8*)vl;
        cacc[dt] = MFMA16(pah, bh8, cacc[dt]);
        cacc[dt] = MFMA16(pah, bl8, cacc[dt]);
        cacc[dt] = MFMA16(pal, bh8, cacc[dt]);
      }
    }
  }
  __syncthreads();                  // B3: all PV reads done before sP reuse
#pragma unroll
  for (int dt = 0; dt < 4; ++dt)
#pragma unroll
    for (int q = 0; q < 4; ++q)
      sP[(wave * 16 + 4 * g2 + q) * 65 + dt * 16 + c] = cacc[dt][q];
  __syncthreads();                  // B4
  {
    const int b2 = bh >> 4, hh = bh & 15;
    for (int o = tid; o < 1024; o += 512) {
      const int r = o >> 6, d = o & 63;
      float a = 0.f;
#pragma unroll
      for (int w = 0; w < 8; ++w) a += sP[(w * 16 + r) * 65 + d];
      attnOut[((size_t)(t0 + r) * 4 + b2) * 1024 + hh * 64 + d] = a;
    }
  }
}

extern "C" void kernel_launch(void* const* d_in, const int* in_sizes, int n_in,
                              void* d_out, int out_size, void* d_ws, size_t ws_size,
                              hipStream_t stream) {
  const float* x     = (const float*)d_in[0];
  const float* w_in  = (const float*)d_in[1];
  const float* b_in  = (const float*)d_in[2];
  const float* w_out = (const float*)d_in[3];
  const float* b_out = (const float*)d_in[4];

  const size_t NP = (size_t)9 * 64 * 1024 * 64;
  _Float16* Ph = (_Float16*)d_ws;
  _Float16* Pl = Ph + NP;
  float* attn = (float*)(Pl + NP);

  (void)hipFuncSetAttribute((const void*)attn_mfma,
                            hipFuncAttributeMaxDynamicSharedMemorySize,
                            SMEM_ATTN);

  // proj = x @ w_in^T + b_in -> fp16 h/l split, head-major; v transposed
  gemm_mfma<1><<<dim3(32, 72), 256, 0, stream>>>(x, w_in, b_in, nullptr, Ph, Pl, 4096, 9216, 1024);
  // fused attention
  attn_mfma<<<4096, 512, SMEM_ATTN, stream>>>(Ph, Pl, attn);
  // out = attn @ w_out^T + b_out
  gemm_mfma<0><<<dim3(32, 8), 256, 0, stream>>>(attn, w_out, b_out, (float*)d_out, nullptr, nullptr, 4096, 1024, 1024);
}

// Round 10
// 1090.342 us; speedup vs baseline: 1.3610x; 1.0381x over previous
//
#include <hip/hip_runtime.h>
#include <math.h>

// ws layout (exactly 160 MiB):
//   Ph: _Float16 [9][64][1024][64]  (72 MiB)  "hi" fp16 split of proj
//   Pl: _Float16 [9][64][1024][64]  (72 MiB)  "lo" fp16 split of proj
//   attn: float [1024][4][1024]     (16 MiB)
// w order: 0=q,1=k,2=v,3=q_left,4=k_left,5=q_right,6=k_right,7=q_local,8=k_local
// layout per matrix: [bh][t][d]  EXCEPT w==2 (v) stored transposed [bh][d][t]

typedef _Float16 half8 __attribute__((ext_vector_type(8)));
typedef _Float16 half4v __attribute__((ext_vector_type(4)));
typedef _Float16 half2v __attribute__((ext_vector_type(2)));
typedef float f32x4 __attribute__((ext_vector_type(4)));

#define MFMA16(A, B, C) __builtin_amdgcn_mfma_f32_16x16x32_f16(A, B, C, 0, 0, 0)

// LDS: sRed 4*128 f32 (2 KB) + sChunk 8 waves*[2][16][40] fp16 (20 KB) + sOut [128][65] f32 (33.3 KB)
#define SMEM_ATTN (512 * 4 + 8 * 2 * 16 * 40 * 2 + 128 * 65 * 4)

static __device__ __forceinline__ unsigned packhl(_Float16 a, _Float16 b) {
  half2v v; v[0] = a; v[1] = b;
  return __builtin_bit_cast(unsigned, v);
}

// ---------------- split-fp16 MFMA GEMM: C = A * B^T + bias ----------------
template<int MODE>
__global__ __launch_bounds__(256, 2)
void gemm_mfma(const float* __restrict__ A, const float* __restrict__ B,
               const float* __restrict__ bias, float* __restrict__ C,
               _Float16* __restrict__ Ph, _Float16* __restrict__ Pl,
               int M, int N, int K) {
  __shared__ _Float16 Ah[128 * 64], Al[128 * 64], Bh[128 * 64], Bl[128 * 64];
  const int tid = threadIdx.x;
  const int m0 = blockIdx.x * 128, n0 = blockIdx.y * 128;
  const int wave = tid >> 6, lane = tid & 63;
  const int g2 = lane >> 4, c = lane & 15;
  const int wm = (wave >> 1) * 64, wn = (wave & 1) * 64;

  const int srow = tid >> 1;
  const int shalf = (tid & 1) * 32;
  const int swz = (srow & 7) << 3;
  const float* ap = A + (size_t)(m0 + srow) * K + shalf;
  const float* bp = B + (size_t)(n0 + srow) * K + shalf;

  f32x4 acc[4][4];
#pragma unroll
  for (int i = 0; i < 4; ++i)
#pragma unroll
    for (int j = 0; j < 4; ++j) acc[i][j] = (f32x4){0.f, 0.f, 0.f, 0.f};

  for (int k0 = 0; k0 < K; k0 += 64) {
    float4 av[8], bv[8];
#pragma unroll
    for (int u = 0; u < 8; ++u) {
      av[u] = *(const float4*)(ap + k0 + u * 4);
      bv[u] = *(const float4*)(bp + k0 + u * 4);
    }
    __syncthreads();
#pragma unroll
    for (int u = 0; u < 8; ++u) {
      const int cc = (shalf + u * 4) ^ swz;
      half4v h4a, l4a, h4b, l4b;
      const float* fa = (const float*)&av[u];
      const float* fb = (const float*)&bv[u];
#pragma unroll
      for (int e = 0; e < 4; ++e) {
        _Float16 ha = (_Float16)fa[e];
        h4a[e] = ha; l4a[e] = (_Float16)(fa[e] - (float)ha);
        _Float16 hb = (_Float16)fb[e];
        h4b[e] = hb; l4b[e] = (_Float16)(fb[e] - (float)hb);
      }
      *(half4v*)&Ah[srow * 64 + cc] = h4a;
      *(half4v*)&Al[srow * 64 + cc] = l4a;
      *(half4v*)&Bh[srow * 64 + cc] = h4b;
      *(half4v*)&Bl[srow * 64 + cc] = l4b;
    }
    __syncthreads();
#pragma unroll
    for (int ks = 0; ks < 2; ++ks) {
      const int kb = ks * 32 + 8 * g2;
      half8 a_h[4], a_l[4];
#pragma unroll
      for (int i = 0; i < 4; ++i) {
        const int row = wm + i * 16 + c;
        const int cc = kb ^ ((row & 7) << 3);
        a_h[i] = *(const half8*)&Ah[row * 64 + cc];
        a_l[i] = *(const half8*)&Al[row * 64 + cc];
      }
#pragma unroll
      for (int j = 0; j < 4; ++j) {
        const int rowb = wn + j * 16 + c;
        const int cc = kb ^ ((rowb & 7) << 3);
        const half8 b_h = *(const half8*)&Bh[rowb * 64 + cc];
        const half8 b_l = *(const half8*)&Bl[rowb * 64 + cc];
#pragma unroll
        for (int i = 0; i < 4; ++i) {
          acc[i][j] = MFMA16(a_h[i], b_h, acc[i][j]);
          acc[i][j] = MFMA16(a_h[i], b_l, acc[i][j]);
          acc[i][j] = MFMA16(a_l[i], b_h, acc[i][j]);
        }
      }
    }
  }

#pragma unroll
  for (int j = 0; j < 4; ++j) {
    const int nj = n0 + wn + j * 16 + c;
    const float bz = bias[nj];
    if (MODE == 0) {
#pragma unroll
      for (int i = 0; i < 4; ++i)
#pragma unroll
        for (int q = 0; q < 4; ++q) {
          const int mi = m0 + wm + i * 16 + 4 * g2 + q;
          C[(size_t)mi * N + nj] = acc[i][j][q] + bz;
        }
    } else {
      const int w = nj >> 10, hh = (nj >> 6) & 15, d = nj & 63;
      const float scale = (w == 0 || w == 7) ? 0.125f : 1.0f;
#pragma unroll
      for (int i = 0; i < 4; ++i)
#pragma unroll
        for (int q = 0; q < 4; ++q) {
          const int mi = m0 + wm + i * 16 + 4 * g2 + q;
          const int t = mi >> 2, b2 = mi & 3;
          const size_t bb = ((size_t)w * 64 + (b2 * 16 + hh)) * 65536;
          const size_t idx = (w == 2) ? bb + (size_t)d * 1024 + t
                                      : bb + (size_t)t * 64 + d;
          const float v = (acc[i][j][q] + bz) * scale;
          const _Float16 h16 = (_Float16)v;
          Ph[idx] = h16;
          Pl[idx] = (_Float16)(v - (float)h16);
        }
    }
  }
}

// -------- fused attention: S^T regs + chunked reg->LDS->MFMA PV, 3 barriers --------
// grid 4096 (XCD-chunked), block 512 (8 waves), LDS 55.8 KB, target 2 WG/CU
// Per wave: lane c = t-row (t0+c); s = sbase + 16*m + 4*g2 + q  (m=tile, q=reg)
__global__ __launch_bounds__(512, 4)
void attn_mfma(const _Float16* __restrict__ Ph, const _Float16* __restrict__ Pl,
               float* __restrict__ attnOut) {
  extern __shared__ float smem[];
  float* sRed = smem;                               // [4][16][8]
  _Float16* sChunk = (_Float16*)(smem + 512);       // [8][2][16][40] fp16
  float* sOut = smem + 512 + 5120;                  // [128][65]
  const int flat = blockIdx.x;
  const int nf = (flat & 7) * 512 + (flat >> 3);    // XCD-chunked
  const int bh = nf >> 6;
  const int t0 = (nf & 63) << 4;
  const int tid = threadIdx.x;
  const int wave = tid >> 6, lane = tid & 63;
  const int g2 = lane >> 4, c = lane & 15;
  const int sbase = wave << 7;

  auto mbase = [&](int w) { return ((size_t)w * 64 + bh) * 65536; };

  struct QF { half8 h0, h1, l0, l1; };
  auto loadQ = [&](int wq) {
    QF f;
    const _Float16* qh = Ph + mbase(wq) + (size_t)(t0 + c) * 64 + 8 * g2;
    const _Float16* ql = Pl + mbase(wq) + (size_t)(t0 + c) * 64 + 8 * g2;
    f.h0 = *(const half8*)qh; f.h1 = *(const half8*)(qh + 32);
    f.l0 = *(const half8*)ql; f.l1 = *(const half8*)(ql + 32);
    return f;
  };
  // transposed score tile: C[s=16*tp+4g2+q][t=c] = K[s]·Q[t] (A=K, B=Q)
  auto stileT = [&](const QF& f, const _Float16* kbh, const _Float16* kbl, int tp) {
    const int s0 = sbase + tp * 16;
    const _Float16* kh = kbh + (size_t)(s0 + c) * 64 + 8 * g2;
    const _Float16* kl = kbl + (size_t)(s0 + c) * 64 + 8 * g2;
    const half8 ah0 = *(const half8*)kh, ah1 = *(const half8*)(kh + 32);
    const half8 al0 = *(const half8*)kl, al1 = *(const half8*)(kl + 32);
    f32x4 a = {0.f, 0.f, 0.f, 0.f};
    a = MFMA16(ah0, f.h0, a);
    a = MFMA16(ah1, f.h1, a);
    a = MFMA16(ah0, f.l0, a);
    a = MFMA16(ah1, f.l1, a);
    a = MFMA16(al0, f.h0, a);
    a = MFMA16(al1, f.h1, a);
    return a;
  };

  auto put = [&](int slot, float val) {
    if (lane < 16) sRed[slot * 128 + c * 8 + wave] = val;
  };
  auto sum_pref = [&](int slot, float& pref) {
    float S = 0.f;
    pref = 0.f;
    const float* p = sRed + slot * 128 + c * 8;
#pragma unroll
    for (int w = 0; w < 8; ++w) {
      const float t = p[w];
      S += t;
      if (w < wave) pref += t;
    }
    return S;
  };
  auto sum_only = [&](int slot) {
    float S = 0.f;
    const float* p = sRed + slot * 128 + c * 8;
#pragma unroll
    for (int w = 0; w < 8; ++w) S += p[w];
    return S;
  };
  // inclusive cumsum along s (regs): q-prefix, g2-scan, tile carry. returns wave total
  auto scan_s = [&](f32x4* v) {
    float carry = 0.f;
#pragma unroll
    for (int m = 0; m < 8; ++m) {
      v[m][1] += v[m][0];
      v[m][2] += v[m][1];
      v[m][3] += v[m][2];
      const float B = v[m][3];
      float sc = B;
      const float u1 = __shfl_up(sc, 16, 64);
      if (g2 >= 1) sc += u1;
      const float u2 = __shfl_up(sc, 32, 64);
      if (g2 >= 2) sc += u2;
      const float e = sc - B + carry;
      v[m][0] += e; v[m][1] += e; v[m][2] += e; v[m][3] += e;
      carry += __shfl(sc, 48 + c, 64);
    }
    return carry;
  };
  auto rowsum = [&](const f32x4* v) {
    float s = 0.f;
#pragma unroll
    for (int m = 0; m < 8; ++m) s += (v[m][0] + v[m][1]) + (v[m][2] + v[m][3]);
    s += __shfl_xor(s, 16, 64);
    s += __shfl_xor(s, 32, 64);
    return s;
  };

  f32x4 lv[8], rv[8];

  // ===== LEFT -> lv (exp, cumsum), RIGHT -> rv (exp, cumsum) =====
  {
    const QF fL = loadQ(3);
    const _Float16* k4h = Ph + mbase(4);
    const _Float16* k4l = Pl + mbase(4);
#pragma unroll
    for (int m = 0; m < 8; ++m) lv[m] = stileT(fL, k4h, k4l, m);
#pragma unroll
    for (int m = 0; m < 8; ++m)
#pragma unroll
      for (int q = 0; q < 4; ++q) lv[m][q] = __expf(lv[m][q]);
    put(0, scan_s(lv));
  }
  {
    const QF fR = loadQ(5);
    const _Float16* k6h = Ph + mbase(6);
    const _Float16* k6l = Pl + mbase(6);
#pragma unroll
    for (int m = 0; m < 8; ++m) rv[m] = stileT(fR, k6h, k6l, m);
#pragma unroll
    for (int m = 0; m < 8; ++m)
#pragma unroll
      for (int q = 0; q < 4; ++q) rv[m][q] = __expf(rv[m][q]);
    put(1, scan_s(rv));
  }
  __syncthreads();                              // B1
  // ===== mask -> lv (drop rv) =====
  {
    float prefL, prefR;
    const float SL = sum_pref(0, prefL);
    const float SR = sum_pref(1, prefR);
    const float invSL = 1.f / SL, invSR = 1.f / SR;
#pragma unroll
    for (int m = 0; m < 8; ++m)
#pragma unroll
      for (int q = 0; q < 4; ++q) {
        lv[m][q] = (lv[m][q] + prefL) * invSL;  // af inclusive, normalized
        rv[m][q] = (rv[m][q] + prefR) * invSR;  // bf inclusive, normalized
      }
    const float bL = prefL * invSL, bR = prefR * invSR;
#pragma unroll
    for (int m = 7; m >= 0; --m) {              // descending: lv[m-1] still af
      const float aU = __shfl_up(lv[m][3], 16, 64);
      const float bU = __shfl_up(rv[m][3], 16, 64);
      const float aM = (m > 0) ? __shfl(lv[m - 1][3], 48 + c, 64) : bL;
      const float bM = (m > 0) ? __shfl(rv[m - 1][3], 48 + c, 64) : bR;
      const float a0 = (g2 == 0) ? aM : aU;
      const float b0 = (g2 == 0) ? bM : bU;
      f32x4 nm;
      nm[0] = lv[m][0] * (1.f - b0)        + (1.f - a0)        * rv[m][0];
      nm[1] = lv[m][1] * (1.f - rv[m][0])  + (1.f - lv[m][0])  * rv[m][1];
      nm[2] = lv[m][2] * (1.f - rv[m][1])  + (1.f - lv[m][1])  * rv[m][2];
      nm[3] = lv[m][3] * (1.f - rv[m][2])  + (1.f - lv[m][2])  * rv[m][3];
      lv[m] = nm;                               // local_mask
    }
  }
  // ===== LOCAL: rv = exp(score)*mask (drop mask after) =====
  {
    const QF fO = loadQ(7);
    const _Float16* k8h = Ph + mbase(8);
    const _Float16* k8l = Pl + mbase(8);
#pragma unroll
    for (int m = 0; m < 8; ++m) {
      const f32x4 x = stileT(fO, k8h, k8l, m);
#pragma unroll
      for (int q = 0; q < 4; ++q) rv[m][q] = __expf(x[q]) * lv[m][q];
    }
    put(2, rowsum(rv));
  }
  // ===== GLOBAL: lv = exp(score) =====
  {
    const QF fG = loadQ(0);
    const _Float16* k1h = Ph + mbase(1);
    const _Float16* k1l = Pl + mbase(1);
#pragma unroll
    for (int m = 0; m < 8; ++m) {
      const f32x4 x = stileT(fG, k1h, k1l, m);
#pragma unroll
      for (int q = 0; q < 4; ++q) lv[m][q] = __expf(x[q]);
    }
    put(3, rowsum(lv));
  }
  __syncthreads();                              // B2
  // ===== P = rv*0.5/SO + lv*0.5/SG -> pack fp16 h/l u32 pairs =====
  unsigned Hp[8][2], Lp[8][2];
  {
    const float scO = 0.5f / sum_only(2);
    const float scG = 0.5f / sum_only(3);
#pragma unroll
    for (int m = 0; m < 8; ++m)
#pragma unroll
      for (int p = 0; p < 2; ++p) {
        const float x0 = rv[m][2 * p] * scO + lv[m][2 * p] * scG;
        const float x1 = rv[m][2 * p + 1] * scO + lv[m][2 * p + 1] * scG;
        const _Float16 h0 = (_Float16)x0, h1 = (_Float16)x1;
        Hp[m][p] = packhl(h0, h1);
        Lp[m][p] = packhl((_Float16)(x0 - (float)h0), (_Float16)(x1 - (float)h1));
      }
  }
  // ===== PV: per 32-s chunk, stage P^T->A-frag via per-wave LDS (no barrier) =====
  f32x4 cacc[4];
#pragma unroll
  for (int dt = 0; dt < 4; ++dt) cacc[dt] = (f32x4){0.f, 0.f, 0.f, 0.f};
  {
    _Float16* chw = sChunk + wave * (2 * 16 * 40);   // [2][16][40]
    const _Float16* vbh = Ph + mbase(2);
    const _Float16* vbl = Pl + mbase(2);
#pragma unroll
    for (int kk = 0; kk < 4; ++kk) {
      // write this chunk: tiles 2kk, 2kk+1; lane writes 4 u32 h + 4 u32 l
#pragma unroll
      for (int mlo = 0; mlo < 2; ++mlo)
#pragma unroll
        for (int p = 0; p < 2; ++p) {
          const int off = c * 40 + 16 * mlo + 4 * g2 + 2 * p;
          *(unsigned*)&chw[off] = Hp[2 * kk + mlo][p];
          *(unsigned*)&chw[640 + off] = Lp[2 * kk + mlo][p];
        }
      // read A fragments (row t=c, k=8g2+j) — compiler inserts lgkmcnt
      const half8 pah = *(const half8*)&chw[c * 40 + 8 * g2];
      const half8 pal = *(const half8*)&chw[640 + c * 40 + 8 * g2];
      const int sk = sbase + kk * 32;
#pragma unroll
      for (int dt = 0; dt < 4; ++dt) {
        const _Float16* vh = vbh + (size_t)(dt * 16 + c) * 1024 + sk + 8 * g2;
        const _Float16* vl = vbl + (size_t)(dt * 16 + c) * 1024 + sk + 8 * g2;
        const half8 bh8 = *(const half8*)vh;
        const half8 bl8 = *(const half8*)vl;
        cacc[dt] = MFMA16(pah, bh8, cacc[dt]);
        cacc[dt] = MFMA16(pah, bl8, cacc[dt]);
        cacc[dt] = MFMA16(pal, bh8, cacc[dt]);
      }
    }
  }
  // partials: rows t=4g2+q (per wave), cols d
#pragma unroll
  for (int dt = 0; dt < 4; ++dt)
#pragma unroll
    for (int q = 0; q < 4; ++q)
      sOut[(wave * 16 + 4 * g2 + q) * 65 + dt * 16 + c] = cacc[dt][q];
  __syncthreads();                  // B3
  {
    const int b2 = bh >> 4, hh = bh & 15;
    for (int o = tid; o < 1024; o += 512) {
      const int r = o >> 6, d = o & 63;
      float a = 0.f;
#pragma unroll
      for (int w = 0; w < 8; ++w) a += sOut[(w * 16 + r) * 65 + d];
      attnOut[((size_t)(t0 + r) * 4 + b2) * 1024 + hh * 64 + d] = a;
    }
  }
}

extern "C" void kernel_launch(void* const* d_in, const int* in_sizes, int n_in,
                              void* d_out, int out_size, void* d_ws, size_t ws_size,
                              hipStream_t stream) {
  const float* x     = (const float*)d_in[0];
  const float* w_in  = (const float*)d_in[1];
  const float* b_in  = (const float*)d_in[2];
  const float* w_out = (const float*)d_in[3];
  const float* b_out = (const float*)d_in[4];

  const size_t NP = (size_t)9 * 64 * 1024 * 64;
  _Float16* Ph = (_Float16*)d_ws;
  _Float16* Pl = Ph + NP;
  float* attn = (float*)(Pl + NP);

  (void)hipFuncSetAttribute((const void*)attn_mfma,
                            hipFuncAttributeMaxDynamicSharedMemorySize,
                            SMEM_ATTN);

  // proj = x @ w_in^T + b_in -> fp16 h/l split, head-major; v transposed
  gemm_mfma<1><<<dim3(32, 72), 256, 0, stream>>>(x, w_in, b_in, nullptr, Ph, Pl, 4096, 9216, 1024);
  // fused attention
  attn_mfma<<<4096, 512, SMEM_ATTN, stream>>>(Ph, Pl, attn);
  // out = attn @ w_out^T + b_out
  gemm_mfma<0><<<dim3(32, 8), 256, 0, stream>>>(attn, w_out, b_out, (float*)d_out, nullptr, nullptr, 4096, 1024, 1024);
}